// Round 2
// baseline (245.888 us; speedup 1.0000x reference)
//
#include <hip/hip_runtime.h>

// LengthRegulator: B=32, T=1024, D=384, T_OUT=4096
// out[b, p, :] = x[b, t(p), :] where t(p) = #{t : ends[t] <= p} (searchsorted
// right of inclusive-cumsum of max(dur,0)), valid for p < min(total, target).
//
// Two-kernel split:
//   lr_index  : per batch, shuffle-scan durations + searchsorted for all 4096
//               output rows -> int16 row table in d_ws (-1 == "write zeros").
//               128 blocks, ~2-4 us, removes scan/search/barriers from hot path.
//   lr_gather : pure gather/stream kernel. One 64 B LDS fill, ONE barrier,
//               low VGPR -> more resident blocks -> HBM saturation.
// Fallback: original fused kernel if ws_size is too small.

#define BB 32
#define TT 1024
#define TOUT 4096
#define D4 96                // float4 per row (384/4)
#define N4 (TOUT * D4)       // 393216 float4 per batch
#define EPB 3072             // float4 per block = exactly 32 rows
#define ROWS_PB 32
#define KPT 12               // float4 per thread (EPB / 256)
#define IDX_GROUPS 4         // lr_index: blocks per batch (1024 rows each)

typedef float v4f __attribute__((ext_vector_type(4)));

// ---------------- kernel 1: duration scan + searchsorted -> int16 table ----
__global__ __launch_bounds__(256) void lr_index(
    const int4* __restrict__ dur4,      // [B, 256] durations as int4
    const int* __restrict__ target_len, // [B]
    short* __restrict__ t_idx)          // [B, TOUT]
{
    __shared__ int s_ends[TT];
    __shared__ int s_wsum[4];
    const int b = blockIdx.x;
    const int g = blockIdx.y;           // row-group: 1024 output rows
    const int tid = threadIdx.x;
    const int lane = tid & 63;
    const int wave = tid >> 6;
    const int tl = target_len[b];

    // in-block duration scan (4 durations/thread, shuffle-based)
    int4 d = dur4[b * 256 + tid];
    const int d0 = d.x > 0 ? d.x : 0;
    const int d1 = d.y > 0 ? d.y : 0;
    const int d2 = d.z > 0 ? d.z : 0;
    const int d3 = d.w > 0 ? d.w : 0;
    const int e0 = d0, e1 = e0 + d1, e2 = e1 + d2, e3 = e2 + d3;

    int v = e3;
    #pragma unroll
    for (int off = 1; off < 64; off <<= 1) {
        int u = __shfl_up(v, off, 64);
        if (lane >= off) v += u;
    }
    if (lane == 63) s_wsum[wave] = v;
    __syncthreads();

    int wbase = 0;
    #pragma unroll
    for (int w = 0; w < 3; ++w) wbase += (w < wave) ? s_wsum[w] : 0;
    const int total = s_wsum[0] + s_wsum[1] + s_wsum[2] + s_wsum[3];
    const int lim = total < tl ? total : tl;

    const int base = wbase + v - e3;  // exclusive prefix for this thread's 4
    ((int4*)s_ends)[tid] = make_int4(base + e0, base + e1, base + e2, base + e3);
    __syncthreads();

    // 4 binary searches per thread (independent -> LDS latency pipelines)
    short* __restrict__ trow_b = t_idx + b * TOUT;
    #pragma unroll
    for (int k = 0; k < 4; ++k) {
        const int p = g * 1024 + k * 256 + tid;
        int lo = 0;
        #pragma unroll
        for (int s = 512; s > 0; s >>= 1) {
            lo += (s_ends[lo + s - 1] <= p) ? s : 0;   // lo stays in [0,1023]
        }
        trow_b[p] = (p < lim) ? (short)lo : (short)-1;
    }
}

// ---------------- kernel 2: pure gather/stream --------------------------
__global__ __launch_bounds__(256) void lr_gather(
    const short* __restrict__ t_idx,    // [B, TOUT]
    const v4f* __restrict__ x,          // [B, T, D4]
    v4f* __restrict__ out)              // [B, TOUT, D4]
{
    __shared__ short s_trow[ROWS_PB];
    const int b = blockIdx.y;
    const int tid = threadIdx.x;
    const int base0 = blockIdx.x * EPB;
    const int p0 = blockIdx.x * ROWS_PB;

    if (tid < ROWS_PB) s_trow[tid] = t_idx[b * TOUT + p0 + tid];
    __syncthreads();

    const v4f* __restrict__ x_b = x + b * TT * D4;
    v4f* __restrict__ out_b = out + b * N4;

    int tt[KPT], cc[KPT];
    #pragma unroll
    for (int k = 0; k < KPT; ++k) {
        const int i = base0 + k * 256 + tid;
        const int p = i / D4;            // magic-mul division
        cc[k] = i - p * D4;
        tt[k] = s_trow[p - p0];          // LDS broadcast; sign-extends
    }

    v4f vv[KPT];
    #pragma unroll
    for (int k = 0; k < KPT; ++k) {
        v4f val = (v4f)(0.f);
        const int t = tt[k];
        if (t >= 0) val = x_b[t * D4 + cc[k]];  // wave-coherent branch
        vv[k] = val;
    }

    #pragma unroll
    for (int k = 0; k < KPT; ++k) {
        __builtin_nontemporal_store(vv[k], out_b + base0 + k * 256 + tid);
    }
}

// ---------------- fallback: original fused kernel -----------------------
__global__ __launch_bounds__(256) void lr_fused(
    const int4* __restrict__ dur4,
    const int* __restrict__ target_len,
    const v4f* __restrict__ x,
    v4f* __restrict__ out)
{
    __shared__ int s_ends[TT];
    __shared__ int s_wsum[4];
    __shared__ int s_trow[ROWS_PB];
    const int b = blockIdx.y;
    const int tid = threadIdx.x;
    const int lane = tid & 63;
    const int wave = tid >> 6;
    const int base0 = blockIdx.x * EPB;
    const int p0 = blockIdx.x * ROWS_PB;

    const int tl = target_len[b];

    int4 d = dur4[b * 256 + tid];
    const int d0 = d.x > 0 ? d.x : 0;
    const int d1 = d.y > 0 ? d.y : 0;
    const int d2 = d.z > 0 ? d.z : 0;
    const int d3 = d.w > 0 ? d.w : 0;
    const int e0 = d0, e1 = e0 + d1, e2 = e1 + d2, e3 = e2 + d3;

    int v = e3;
    #pragma unroll
    for (int off = 1; off < 64; off <<= 1) {
        int u = __shfl_up(v, off, 64);
        if (lane >= off) v += u;
    }
    if (lane == 63) s_wsum[wave] = v;
    __syncthreads();

    int wbase = 0;
    #pragma unroll
    for (int w = 0; w < 3; ++w) wbase += (w < wave) ? s_wsum[w] : 0;
    const int total = s_wsum[0] + s_wsum[1] + s_wsum[2] + s_wsum[3];
    const int lim = total < tl ? total : tl;

    const int base = wbase + v - e3;
    ((int4*)s_ends)[tid] = make_int4(base + e0, base + e1, base + e2, base + e3);
    __syncthreads();

    if (tid < ROWS_PB) {
        const int p = p0 + tid;
        int lo = 0;
        #pragma unroll
        for (int s = 512; s > 0; s >>= 1) {
            lo += (s_ends[lo + s - 1] <= p) ? s : 0;
        }
        s_trow[tid] = lo;
    }
    __syncthreads();

    const v4f* __restrict__ x_b = x + b * TT * D4;
    v4f* __restrict__ out_b = out + b * N4;

    int pp[KPT], ccc[KPT], ttt[KPT];
    v4f vv[KPT];
    #pragma unroll
    for (int k = 0; k < KPT; ++k) {
        const int i = base0 + k * 256 + tid;
        const int p = i / D4;
        pp[k] = p;
        ccc[k] = i - p * D4;
        ttt[k] = s_trow[p - p0];
    }
    #pragma unroll
    for (int k = 0; k < KPT; ++k) {
        vv[k] = x_b[ttt[k] * D4 + ccc[k]];
    }
    #pragma unroll
    for (int k = 0; k < KPT; ++k) {
        if (pp[k] >= lim) vv[k] = (v4f)(0.f);
        __builtin_nontemporal_store(vv[k], out_b + base0 + k * 256 + tid);
    }
}

extern "C" void kernel_launch(void* const* d_in, const int* in_sizes, int n_in,
                              void* d_out, int out_size, void* d_ws, size_t ws_size,
                              hipStream_t stream) {
    const float* x        = (const float*)d_in[0];
    const int* durations  = (const int*)d_in[1];
    const int* target_len = (const int*)d_in[2];
    float* out            = (float*)d_out;

    const size_t need = (size_t)BB * TOUT * sizeof(short);  // 256 KB
    if (d_ws != nullptr && ws_size >= need) {
        short* t_idx = (short*)d_ws;
        lr_index<<<dim3(BB, IDX_GROUPS), 256, 0, stream>>>(
            (const int4*)durations, target_len, t_idx);
        lr_gather<<<dim3(N4 / EPB, BB), 256, 0, stream>>>(
            t_idx, (const v4f*)x, (v4f*)out);
    } else {
        lr_fused<<<dim3(N4 / EPB, BB), 256, 0, stream>>>(
            (const int4*)durations, target_len, (const v4f*)x, (v4f*)out);
    }
}